// Round 7
// baseline (192.744 us; speedup 1.0000x reference)
//
#include <hip/hip_runtime.h>
#include <stdint.h>

#define NH   8
#define DIM  512
#define NP   1024
#define MNP  4096
#define BS   4
#define TOPK 32
#define DH   64

typedef unsigned short u16;
typedef __attribute__((ext_vector_type(8))) short bf16x8;
typedef __attribute__((ext_vector_type(4))) float f32x4;

__device__ __forceinline__ u16 f2bf(float f) {
    union { float f; unsigned u; } x; x.f = f;
    unsigned r = x.u + 0x7FFFu + ((x.u >> 16) & 1u);   // RNE
    return (u16)(r >> 16);
}
__device__ __forceinline__ float bf2f(u16 h) {
    union { unsigned u; float f; } x; x.u = ((unsigned)h) << 16;
    return x.f;
}

// async 16B global -> LDS (global_load_lds_dwordx4), wave-uniform base + lane*16
__device__ __forceinline__ void async16(const void* g, void* l) {
    __builtin_amdgcn_global_load_lds(
        (const __attribute__((address_space(1))) unsigned int*)g,
        (__attribute__((address_space(3))) unsigned int*)l, 16, 0, 0);
}

// ---------------- single fp32 -> bf16 pass: W1|W2|W3 -> wall, q|k|v -> act
__global__ void cvt_all(const float* __restrict__ W1, const float* __restrict__ W2,
                        const float* __restrict__ W3, const float* __restrict__ q,
                        const float* __restrict__ k,  const float* __restrict__ v,
                        u16* __restrict__ wall, u16* __restrict__ act) {
    const size_t base = ((size_t)blockIdx.x * 256 + threadIdx.x) * 4;
    const size_t gstride = (size_t)4800 * 256 * 4;   // elems per pass
#pragma unroll
    for (int g = 0; g < 4; g++) {
        size_t i = base + (size_t)g * gstride;
        const float* s; u16* d;
        if (i < 786432) {
            d = wall + i;
            s = (i < 262144) ? W1 + i : (i < 524288) ? W2 + (i - 262144) : W3 + (i - 524288);
        } else {
            size_t j = i - 786432;
            d = act + j;
            s = (j < 2097152) ? q + j : (j < 10485760) ? k + (j - 2097152) : v + (j - 10485760);
        }
        float4 val = *(const float4*)s;
        ushort4 o;
        o.x = f2bf(val.x); o.y = f2bf(val.y); o.z = f2bf(val.z); o.w = f2bf(val.w);
        *(ushort4*)d = o;
    }
}

// ---------------- projection GEMM: BM=256 BN=256 BK=32, 512 threads (8 waves,
// 2m x 4n, 128x64 per wave).  Staged-byte reduction: every prior round sat at
// a ~6.5 TB/s staging-supply ceiling (r0: 302MB/45us, r3: 223MB/34us,
// r6: 223MB/35us despite 2x occupancy) -> the lever is BYTES, not pipeline.
// BN=256 halves act re-fetch: staged = 75.5 (act) + 72 (W) = 148 MB.
// acc[8][4] = 128 VGPRs -> launch_bounds(512,2) (256-reg cap; r5's (512,6)
// 85-reg cap spilled acc to scratch).  8 waves/CU — the occupancy that already
// saturated the BW wall in r0-r3.  Counted vmcnt(4) pipeline (T4); BK=32 rows
// pair-packed into 64-u16 phys rows XOR-swizzled by phys&7 (r5/r6-verified).
__global__ __launch_bounds__(512, 2)
void proj_gemm(const u16* __restrict__ act, const u16* __restrict__ wall,
               const float* __restrict__ b1, const float* __restrict__ b2,
               const float* __restrict__ b3, u16* __restrict__ outall) {
    __shared__ u16 As[2][128 * 64];    // 256 rows pair-packed -> 128 phys x 64
    __shared__ u16 Bs[2][128 * 64];    // 256 rows pair-packed -> 128 phys x 64

    const int bid = blockIdx.x;        // 0..287
    const int x = bid / 144;           // n-tile 0..1; same-m pair 144 apart
    const int t = bid % 144;           //   (144%8==0 -> same XCD round-robin)
    int z, y;
    if (t < 16)      { z = 0; y = t; }           // q: M=4096  (16 tiles)
    else if (t < 80) { z = 1; y = t - 16; }      // k: M=16384 (64 tiles)
    else             { z = 2; y = t - 80; }      // v: M=16384 (64 tiles)

    const size_t aoff = (z == 0) ? 0u : (z == 1) ? 2097152u : 10485760u;
    const u16* A = act + aoff;
    const u16* W = wall + (size_t)z * 262144;
    const float* bias = (z == 0) ? b1 : (z == 1) ? b2 : b3;
    u16* C = outall + aoff;

    const int tid  = threadIdx.x;      // 0..511
    const int bm   = y * 256;
    const int bn   = x * 256;
    const int wave = tid >> 6;
    const int lane = tid & 63;
    const int wm   = (wave & 1) * 128; // 2 m-waves
    const int wn   = (wave >> 1) * 64; // 4 n-waves
    const int l16  = lane & 15;
    const int quad = lane >> 4;

    // staging: granule L in {tid, tid+512} (1024 granules per matrix tile).
    // granule L -> phys row p=L>>3, slot q3=L&7; logical pos = q3 ^ (p&7),
    // half h=pos>>2, k-granule g=pos&3; logical row r = 2p+h.
    // L=tid+512: (p+64)&7 == p&7 -> same pos -> row r+128, same g.
    const int pA  = tid >> 3;                  // 0..63
    const int q3  = tid & 7;
    const int pos = q3 ^ (pA & 7);
    const int hh  = pos >> 2;
    const int gg  = pos & 3;
    const int rr  = 2 * pA + hh;               // 0..127 (+128 for 2nd granule)
    const u16* Asrc = A + (size_t)(bm + rr) * 512 + gg * 8;
    const u16* Bsrc = W + (size_t)(bn + rr) * 512 + gg * 8;

    f32x4 acc[8][4] = {};

    // 4 async16 per thread per stage (2 A + 2 B)
    #define STAGE(buf, k0)                                                     \
        async16(Asrc + (k0),             &As[buf][tid * 8]);                   \
        async16(Asrc + 128 * 512 + (k0), &As[buf][tid * 8 + 4096]);            \
        async16(Bsrc + (k0),             &Bs[buf][tid * 8]);                   \
        async16(Bsrc + 128 * 512 + (k0), &Bs[buf][tid * 8 + 4096]);

    STAGE(0, 0);

#pragma unroll
    for (int kt = 0; kt < 16; kt++) {
        const int cur = kt & 1;
        if (kt < 15) {
            STAGE(cur ^ 1, (kt + 1) * 32);   // prefetch next tile (other buffer)
            // wait tile kt's 4 loads (issued last iter); keep kt+1's 4 in flight
            asm volatile("s_waitcnt vmcnt(4)" ::: "memory");
        } else {
            asm volatile("s_waitcnt vmcnt(0)" ::: "memory");
        }
        __builtin_amdgcn_s_barrier();        // all waves: tile kt resident
        {
            bf16x8 af[8], bfr[4];
#pragma unroll
            for (int i = 0; i < 8; i++) {
                int ra = wm + i * 16 + l16;          // 0..255
                af[i] = *(const bf16x8*)(&As[cur][(ra >> 1) * 64 +
                          (((((ra & 1) << 2) | quad) ^ ((ra >> 1) & 7)) << 3)]);
            }
#pragma unroll
            for (int j = 0; j < 4; j++) {
                int rb = wn + j * 16 + l16;          // 0..255
                bfr[j] = *(const bf16x8*)(&Bs[cur][(rb >> 1) * 64 +
                          (((((rb & 1) << 2) | quad) ^ ((rb >> 1) & 7)) << 3)]);
            }
#pragma unroll
            for (int i = 0; i < 8; i++)
#pragma unroll
                for (int j = 0; j < 4; j++)
                    acc[i][j] = __builtin_amdgcn_mfma_f32_16x16x32_bf16(
                        af[i], bfr[j], acc[i][j], 0, 0, 0);
        }
        // all waves done reading buf cur before next iter's STAGE overwrites it
        __builtin_amdgcn_s_barrier();
    }
    #undef STAGE

    // C/D layout: col=lane&15, row=quad*4+reg
#pragma unroll
    for (int i = 0; i < 8; i++) {
        int row = bm + wm + i * 16 + quad * 4;
#pragma unroll
        for (int j = 0; j < 4; j++) {
            int col = bn + wn + j * 16 + l16;
            float bv = bias[col];
#pragma unroll
            for (int r = 0; r < 4; r++)
                C[(size_t)(row + r) * 512 + col] = f2bf(acc[i][j][r] + bv);
        }
    }
}

// ---------------- barrier-free top-k gather attention: one WAVE per (n,b)
__global__ __launch_bounds__(256)
void attn_kernel(const u16* __restrict__ Qh, const u16* __restrict__ Kh,
                 const u16* __restrict__ Vh, const int* __restrict__ rns,
                 float* __restrict__ out) {
    __shared__ float sq[4][512];        // q row fp32, wave-private
    __shared__ float swt[4][32 * 9];    // weights [slot][head], stride-9 pad
    __shared__ int   srw[4][TOPK];      // gathered row offsets

    const int wv   = threadIdx.x >> 6;
    const int lane = threadIdx.x & 63;
    const int pair = blockIdx.x * 4 + wv;   // (n,b) id
    const int n = pair >> 2;
    const int b = pair & 3;
    const int s   = lane >> 1;   // slot
    const int sub = lane & 1;    // dim half

    int myidx = rns[(b * NP + n) * TOPK + s];
    int myrow = (myidx * BS + b) * DIM;
    if (sub == 0) srw[wv][s] = myrow;

    // dedupe: dup iff an earlier slot has the same index (matches ref set-mask)
    bool dup = false;
#pragma unroll
    for (int j = 0; j < TOPK; j++) {
        int other = __shfl(myidx, j * 2, 64);
        dup = dup || ((j < s) && (other == myidx));
    }

    // q row -> LDS fp32 (16B bf16 load per lane)
    {
        const u16* qrow = Qh + (size_t)pair * DIM;
        uint4 qv = *(const uint4*)(qrow + lane * 8);
        float4 f0 = { bf2f((u16)qv.x), bf2f((u16)(qv.x >> 16)),
                      bf2f((u16)qv.y), bf2f((u16)(qv.y >> 16)) };
        float4 f1 = { bf2f((u16)qv.z), bf2f((u16)(qv.z >> 16)),
                      bf2f((u16)qv.w), bf2f((u16)(qv.w >> 16)) };
        *(float4*)(&sq[wv][lane * 8])     = f0;
        *(float4*)(&sq[wv][lane * 8 + 4]) = f1;
    }
    __builtin_amdgcn_wave_barrier();   // wave-private LDS: scheduling pin only

    // scores: each lane computes 8 half-dots (its slot, its 32-dim half)
    const float* qw = sq[wv];
    float sc[NH];
#pragma unroll
    for (int h = 0; h < NH; h++) {
        const u16* kp = Kh + myrow + h * DH + sub * 32;
        const float* qp = qw + h * DH + sub * 32;
        float acc = 0.f;
#pragma unroll
        for (int d = 0; d < 32; d += 8) {
            uint4 kv = *(const uint4*)(kp + d);
            acc += qp[d + 0] * bf2f((u16)kv.x) + qp[d + 1] * bf2f((u16)(kv.x >> 16))
                 + qp[d + 2] * bf2f((u16)kv.y) + qp[d + 3] * bf2f((u16)(kv.y >> 16))
                 + qp[d + 4] * bf2f((u16)kv.z) + qp[d + 5] * bf2f((u16)(kv.z >> 16))
                 + qp[d + 6] * bf2f((u16)kv.w) + qp[d + 7] * bf2f((u16)(kv.w >> 16));
        }
        sc[h] = acc;
    }
#pragma unroll
    for (int h = 0; h < NH; h++) {
        sc[h] += __shfl_xor(sc[h], 1, 64);
        sc[h] = dup ? -1e30f : sc[h] * 0.125f;
    }
    // softmax over 32 slots via stride-{2..32} butterflies
    float w[NH];
#pragma unroll
    for (int h = 0; h < NH; h++) {
        float m = sc[h];
        m = fmaxf(m, __shfl_xor(m, 2, 64));
        m = fmaxf(m, __shfl_xor(m, 4, 64));
        m = fmaxf(m, __shfl_xor(m, 8, 64));
        m = fmaxf(m, __shfl_xor(m, 16, 64));
        m = fmaxf(m, __shfl_xor(m, 32, 64));
        float e = __expf(sc[h] - m);
        float t = e;
        t += __shfl_xor(t, 2, 64);
        t += __shfl_xor(t, 4, 64);
        t += __shfl_xor(t, 8, 64);
        t += __shfl_xor(t, 16, 64);
        t += __shfl_xor(t, 32, 64);
        w[h] = e / t;
    }
    if (sub == 0) {
#pragma unroll
        for (int h = 0; h < NH; h++) swt[wv][s * 9 + h] = w[h];
    }
    __builtin_amdgcn_wave_barrier();

    // V phase: lane covers 8 output elems (16B V load) x 32 slots
    const int h  = lane >> 3;
    const int e8 = lane * 8;
    float a[8] = {0, 0, 0, 0, 0, 0, 0, 0};
#pragma unroll 8
    for (int si = 0; si < TOPK; si++) {
        int   row = srw[wv][si];              // broadcast read
        float wgt = swt[wv][si * 9 + h];      // 8 consecutive addrs: no conflict
        uint4 vv = *(const uint4*)(Vh + row + e8);
        a[0] += wgt * bf2f((u16)vv.x); a[1] += wgt * bf2f((u16)(vv.x >> 16));
        a[2] += wgt * bf2f((u16)vv.y); a[3] += wgt * bf2f((u16)(vv.y >> 16));
        a[4] += wgt * bf2f((u16)vv.z); a[5] += wgt * bf2f((u16)(vv.z >> 16));
        a[6] += wgt * bf2f((u16)vv.w); a[7] += wgt * bf2f((u16)(vv.w >> 16));
    }
    float* op = out + (size_t)pair * DIM + e8;
    float4 o0 = {a[0], a[1], a[2], a[3]};
    float4 o1 = {a[4], a[5], a[6], a[7]};
    *(float4*)op       = o0;
    *((float4*)op + 1) = o1;
}

extern "C" void kernel_launch(void* const* d_in, const int* in_sizes, int n_in,
                              void* d_out, int out_size, void* d_ws, size_t ws_size,
                              hipStream_t stream) {
    const float* q  = (const float*)d_in[0];
    const float* k  = (const float*)d_in[1];
    const float* v  = (const float*)d_in[2];
    const int* rns  = (const int*)d_in[3];
    const float* W1 = (const float*)d_in[4];
    const float* b1 = (const float*)d_in[5];
    const float* W2 = (const float*)d_in[6];
    const float* b2 = (const float*)d_in[7];
    const float* W3 = (const float*)d_in[8];
    const float* b3 = (const float*)d_in[9];
    float* out = (float*)d_out;

    u16* ws   = (u16*)d_ws;
    u16* wall = ws;                        // 3 * 512*512 bf16 weights
    u16* act  = wall + 786432;             // q(2097152) | k(8388608) | v(8388608)
    u16* proj = act + 18874368;            // Qh | Kh | Vh, same offsets
    u16* Qh = proj;
    u16* Kh = proj + 2097152;
    u16* Vh = proj + 10485760;

    cvt_all<<<4800, 256, 0, stream>>>(W1, W2, W3, q, k, v, wall, act);
    proj_gemm<<<288, 512, 0, stream>>>(act, wall, b1, b2, b3, proj);
    attn_kernel<<<NP * BS / 4, 256, 0, stream>>>(Qh, Kh, Vh, rns, out);
}

// Round 8
// 187.195 us; speedup vs baseline: 1.0296x; 1.0296x over previous
//
#include <hip/hip_runtime.h>
#include <stdint.h>

#define NH   8
#define DIM  512
#define NP   1024
#define MNP  4096
#define BS   4
#define TOPK 32
#define DH   64

typedef unsigned short u16;
typedef __attribute__((ext_vector_type(8))) short bf16x8;
typedef __attribute__((ext_vector_type(4))) float f32x4;

__device__ __forceinline__ u16 f2bf(float f) {
    union { float f; unsigned u; } x; x.f = f;
    unsigned r = x.u + 0x7FFFu + ((x.u >> 16) & 1u);   // RNE
    return (u16)(r >> 16);
}
__device__ __forceinline__ float bf2f(u16 h) {
    union { unsigned u; float f; } x; x.u = ((unsigned)h) << 16;
    return x.f;
}

// async 16B global -> LDS (global_load_lds_dwordx4), wave-uniform base + lane*16
__device__ __forceinline__ void async16(const void* g, void* l) {
    __builtin_amdgcn_global_load_lds(
        (const __attribute__((address_space(1))) unsigned int*)g,
        (__attribute__((address_space(3))) unsigned int*)l, 16, 0, 0);
}

// ---------------- single fp32 -> bf16 pass: W1|W2|W3 -> wall, q|k|v -> act
__global__ void cvt_all(const float* __restrict__ W1, const float* __restrict__ W2,
                        const float* __restrict__ W3, const float* __restrict__ q,
                        const float* __restrict__ k,  const float* __restrict__ v,
                        u16* __restrict__ wall, u16* __restrict__ act) {
    const size_t base = ((size_t)blockIdx.x * 256 + threadIdx.x) * 4;
    const size_t gstride = (size_t)4800 * 256 * 4;   // elems per pass
#pragma unroll
    for (int g = 0; g < 4; g++) {
        size_t i = base + (size_t)g * gstride;
        const float* s; u16* d;
        if (i < 786432) {
            d = wall + i;
            s = (i < 262144) ? W1 + i : (i < 524288) ? W2 + (i - 262144) : W3 + (i - 524288);
        } else {
            size_t j = i - 786432;
            d = act + j;
            s = (j < 2097152) ? q + j : (j < 10485760) ? k + (j - 2097152) : v + (j - 10485760);
        }
        float4 val = *(const float4*)s;
        ushort4 o;
        o.x = f2bf(val.x); o.y = f2bf(val.y); o.z = f2bf(val.z); o.w = f2bf(val.w);
        *(ushort4*)d = o;
    }
}

// ---------------- projection GEMM: BM=256 BN=128 BK=32, 512 threads (8 waves,
// 4m x 2n, 64x64 each) — the r6 shape (2 blocks/CU, 576 blocks = 1.125
// rounds, 223 MB staged), now TRIPLE-BUFFERED with prefetch depth 2:
// steady state keeps 9 loads in flight (tiles t,t+1,t+2 x 3) and waits
// vmcnt(6); tile t's loads were issued TWO iterations (~800+ cyc) earlier,
// above worst-case L2/HBM latency.  (r7 lesson: BM=BN=256 forces 244 unified
// regs -> 1 block/CU -> 2 grid rounds; feasible byte floor at >=2 blocks/CU
// is this shape.)  LDS 72 KB x 2 blocks = 144 <= 160 KB: occupancy kept.
// launch_bounds(512,4): 128-reg cap (64 VGPR + 64 AGPR acc, spill-free).
// BK=32 rows pair-packed into 64-u16 phys rows XOR-swizzled by phys&7:
// gload_lds dest linear (G21), ds_read 2-way bank-aliased = free (m136).
__global__ __launch_bounds__(512, 4)
void proj_gemm(const u16* __restrict__ act, const u16* __restrict__ wall,
               const float* __restrict__ b1, const float* __restrict__ b2,
               const float* __restrict__ b3, u16* __restrict__ outall) {
    __shared__ u16 As[3][128 * 64];    // 256 rows pair-packed -> 128 phys x 64
    __shared__ u16 Bs[3][64 * 64];     // 128 rows pair-packed ->  64 phys x 64

    const int bid = blockIdx.x;        // 0..575
    const int x = bid / 144;           // n-tile; same-m blocks 144 apart (144%8==0
    const int t = bid % 144;           //   -> share an XCD L2 under round-robin)
    int z, y;
    if (t < 16)      { z = 0; y = t; }           // q: M=4096  (16 tiles)
    else if (t < 80) { z = 1; y = t - 16; }      // k: M=16384 (64 tiles)
    else             { z = 2; y = t - 80; }      // v: M=16384 (64 tiles)

    const size_t aoff = (z == 0) ? 0u : (z == 1) ? 2097152u : 10485760u;
    const u16* A = act + aoff;
    const u16* W = wall + (size_t)z * 262144;
    const float* bias = (z == 0) ? b1 : (z == 1) ? b2 : b3;
    u16* C = outall + aoff;

    const int tid  = threadIdx.x;      // 0..511
    const int bm   = y * 256;
    const int bn   = x * 128;
    const int wave = tid >> 6;
    const int lane = tid & 63;
    const int wm   = (wave & 3) * 64;  // 4 m-waves
    const int wn   = (wave >> 2) * 64; // 2 n-waves
    const int l16  = lane & 15;
    const int quad = lane >> 4;

    // staging: LDS granule L=tid (and L=tid+512 for A's upper half).
    // granule L -> phys row p=L>>3, slot q3=L&7; logical pos = q3 ^ (p&7),
    // half h=pos>>2, k-granule g=pos&3; logical row r = 2p+h.
    const int pA   = tid >> 3;                 // 0..63
    const int q3   = tid & 7;
    const int posA = q3 ^ (pA & 7);
    const int hA   = posA >> 2;
    const int gA   = posA & 3;
    const int rA   = 2 * pA + hA;              // 0..127 (+128 for 2nd A chunk)
    const u16* Asrc = A + (size_t)(bm + rA) * 512 + gA * 8;
    const u16* Bsrc = W + (size_t)(bn + rA) * 512 + gA * 8;   // B rows 0..127

    f32x4 acc[4][4] = {};

    // 3 async16 per thread per stage (2 A halves + 1 B)
    #define STAGE(buf, k0)                                                     \
        async16(Asrc + (k0),               &As[buf][tid * 8]);                 \
        async16(Asrc + 128 * 512 + (k0),   &As[buf][tid * 8 + 4096]);          \
        async16(Bsrc + (k0),               &Bs[buf][tid * 8]);

    STAGE(0, 0);
    STAGE(1, 32);

#pragma unroll
    for (int kt = 0; kt < 16; kt++) {
        const int cur = kt % 3;
        if (kt < 14) {
            STAGE((kt + 2) % 3, (kt + 2) * 32);  // prefetch tile kt+2
            // in flight: kt(3) + kt+1(3) + kt+2(3) = 9; retire tile kt's 3
            asm volatile("s_waitcnt vmcnt(6)" ::: "memory");
        } else if (kt == 14) {
            // in flight: kt(3) + kt+1(3) = 6; retire tile kt's 3
            asm volatile("s_waitcnt vmcnt(3)" ::: "memory");
        } else {
            asm volatile("s_waitcnt vmcnt(0)" ::: "memory");
        }
        __builtin_amdgcn_s_barrier();        // all waves: tile kt resident
        {
            bf16x8 af[4], bfr[4];
#pragma unroll
            for (int i = 0; i < 4; i++) {
                int ra = wm + i * 16 + l16;          // 0..255
                af[i] = *(const bf16x8*)(&As[cur][(ra >> 1) * 64 +
                          (((((ra & 1) << 2) | quad) ^ ((ra >> 1) & 7)) << 3)]);
            }
#pragma unroll
            for (int j = 0; j < 4; j++) {
                int rb = wn + j * 16 + l16;          // 0..127
                bfr[j] = *(const bf16x8*)(&Bs[cur][(rb >> 1) * 64 +
                          (((((rb & 1) << 2) | quad) ^ ((rb >> 1) & 7)) << 3)]);
            }
#pragma unroll
            for (int i = 0; i < 4; i++)
#pragma unroll
                for (int j = 0; j < 4; j++)
                    acc[i][j] = __builtin_amdgcn_mfma_f32_16x16x32_bf16(
                        af[i], bfr[j], acc[i][j], 0, 0, 0);
        }
        // buffer cur is overwritten by STAGE issued at iter kt+1 (tile kt+3),
        // i.e. after this barrier: all waves have finished reading it.
        __builtin_amdgcn_s_barrier();
    }
    #undef STAGE

    // C/D layout: col=lane&15, row=quad*4+reg
#pragma unroll
    for (int i = 0; i < 4; i++) {
        int row = bm + wm + i * 16 + quad * 4;
#pragma unroll
        for (int j = 0; j < 4; j++) {
            int col = bn + wn + j * 16 + l16;
            float bv = bias[col];
#pragma unroll
            for (int r = 0; r < 4; r++)
                C[(size_t)(row + r) * 512 + col] = f2bf(acc[i][j][r] + bv);
        }
    }
}

// ---------------- barrier-free top-k gather attention: one WAVE per (n,b)
__global__ __launch_bounds__(256)
void attn_kernel(const u16* __restrict__ Qh, const u16* __restrict__ Kh,
                 const u16* __restrict__ Vh, const int* __restrict__ rns,
                 float* __restrict__ out) {
    __shared__ float sq[4][512];        // q row fp32, wave-private
    __shared__ float swt[4][32 * 9];    // weights [slot][head], stride-9 pad
    __shared__ int   srw[4][TOPK];      // gathered row offsets

    const int wv   = threadIdx.x >> 6;
    const int lane = threadIdx.x & 63;
    const int pair = blockIdx.x * 4 + wv;   // (n,b) id
    const int n = pair >> 2;
    const int b = pair & 3;
    const int s   = lane >> 1;   // slot
    const int sub = lane & 1;    // dim half

    int myidx = rns[(b * NP + n) * TOPK + s];
    int myrow = (myidx * BS + b) * DIM;
    if (sub == 0) srw[wv][s] = myrow;

    // dedupe: dup iff an earlier slot has the same index (matches ref set-mask)
    bool dup = false;
#pragma unroll
    for (int j = 0; j < TOPK; j++) {
        int other = __shfl(myidx, j * 2, 64);
        dup = dup || ((j < s) && (other == myidx));
    }

    // q row -> LDS fp32 (16B bf16 load per lane)
    {
        const u16* qrow = Qh + (size_t)pair * DIM;
        uint4 qv = *(const uint4*)(qrow + lane * 8);
        float4 f0 = { bf2f((u16)qv.x), bf2f((u16)(qv.x >> 16)),
                      bf2f((u16)qv.y), bf2f((u16)(qv.y >> 16)) };
        float4 f1 = { bf2f((u16)qv.z), bf2f((u16)(qv.z >> 16)),
                      bf2f((u16)qv.w), bf2f((u16)(qv.w >> 16)) };
        *(float4*)(&sq[wv][lane * 8])     = f0;
        *(float4*)(&sq[wv][lane * 8 + 4]) = f1;
    }
    __builtin_amdgcn_wave_barrier();   // wave-private LDS: scheduling pin only

    // scores: each lane computes 8 half-dots (its slot, its 32-dim half)
    const float* qw = sq[wv];
    float sc[NH];
#pragma unroll
    for (int h = 0; h < NH; h++) {
        const u16* kp = Kh + myrow + h * DH + sub * 32;
        const float* qp = qw + h * DH + sub * 32;
        float acc = 0.f;
#pragma unroll
        for (int d = 0; d < 32; d += 8) {
            uint4 kv = *(const uint4*)(kp + d);
            acc += qp[d + 0] * bf2f((u16)kv.x) + qp[d + 1] * bf2f((u16)(kv.x >> 16))
                 + qp[d + 2] * bf2f((u16)kv.y) + qp[d + 3] * bf2f((u16)(kv.y >> 16))
                 + qp[d + 4] * bf2f((u16)kv.z) + qp[d + 5] * bf2f((u16)(kv.z >> 16))
                 + qp[d + 6] * bf2f((u16)kv.w) + qp[d + 7] * bf2f((u16)(kv.w >> 16));
        }
        sc[h] = acc;
    }
#pragma unroll
    for (int h = 0; h < NH; h++) {
        sc[h] += __shfl_xor(sc[h], 1, 64);
        sc[h] = dup ? -1e30f : sc[h] * 0.125f;
    }
    // softmax over 32 slots via stride-{2..32} butterflies
    float w[NH];
#pragma unroll
    for (int h = 0; h < NH; h++) {
        float m = sc[h];
        m = fmaxf(m, __shfl_xor(m, 2, 64));
        m = fmaxf(m, __shfl_xor(m, 4, 64));
        m = fmaxf(m, __shfl_xor(m, 8, 64));
        m = fmaxf(m, __shfl_xor(m, 16, 64));
        m = fmaxf(m, __shfl_xor(m, 32, 64));
        float e = __expf(sc[h] - m);
        float t = e;
        t += __shfl_xor(t, 2, 64);
        t += __shfl_xor(t, 4, 64);
        t += __shfl_xor(t, 8, 64);
        t += __shfl_xor(t, 16, 64);
        t += __shfl_xor(t, 32, 64);
        w[h] = e / t;
    }
    if (sub == 0) {
#pragma unroll
        for (int h = 0; h < NH; h++) swt[wv][s * 9 + h] = w[h];
    }
    __builtin_amdgcn_wave_barrier();

    // V phase: lane covers 8 output elems (16B V load) x 32 slots
    const int h  = lane >> 3;
    const int e8 = lane * 8;
    float a[8] = {0, 0, 0, 0, 0, 0, 0, 0};
#pragma unroll 8
    for (int si = 0; si < TOPK; si++) {
        int   row = srw[wv][si];              // broadcast read
        float wgt = swt[wv][si * 9 + h];      // 8 consecutive addrs: no conflict
        uint4 vv = *(const uint4*)(Vh + row + e8);
        a[0] += wgt * bf2f((u16)vv.x); a[1] += wgt * bf2f((u16)(vv.x >> 16));
        a[2] += wgt * bf2f((u16)vv.y); a[3] += wgt * bf2f((u16)(vv.y >> 16));
        a[4] += wgt * bf2f((u16)vv.z); a[5] += wgt * bf2f((u16)(vv.z >> 16));
        a[6] += wgt * bf2f((u16)vv.w); a[7] += wgt * bf2f((u16)(vv.w >> 16));
    }
    float* op = out + (size_t)pair * DIM + e8;
    float4 o0 = {a[0], a[1], a[2], a[3]};
    float4 o1 = {a[4], a[5], a[6], a[7]};
    *(float4*)op       = o0;
    *((float4*)op + 1) = o1;
}

extern "C" void kernel_launch(void* const* d_in, const int* in_sizes, int n_in,
                              void* d_out, int out_size, void* d_ws, size_t ws_size,
                              hipStream_t stream) {
    const float* q  = (const float*)d_in[0];
    const float* k  = (const float*)d_in[1];
    const float* v  = (const float*)d_in[2];
    const int* rns  = (const int*)d_in[3];
    const float* W1 = (const float*)d_in[4];
    const float* b1 = (const float*)d_in[5];
    const float* W2 = (const float*)d_in[6];
    const float* b2 = (const float*)d_in[7];
    const float* W3 = (const float*)d_in[8];
    const float* b3 = (const float*)d_in[9];
    float* out = (float*)d_out;

    u16* ws   = (u16*)d_ws;
    u16* wall = ws;                        // 3 * 512*512 bf16 weights
    u16* act  = wall + 786432;             // q(2097152) | k(8388608) | v(8388608)
    u16* proj = act + 18874368;            // Qh | Kh | Vh, same offsets
    u16* Qh = proj;
    u16* Kh = proj + 2097152;
    u16* Vh = proj + 10485760;

    cvt_all<<<4800, 256, 0, stream>>>(W1, W2, W3, q, k, v, wall, act);
    proj_gemm<<<576, 512, 0, stream>>>(act, wall, b1, b2, b3, proj);
    attn_kernel<<<NP * BS / 4, 256, 0, stream>>>(Qh, Kh, Vh, rns, out);
}

// Round 9
// 185.111 us; speedup vs baseline: 1.0412x; 1.0113x over previous
//
#include <hip/hip_runtime.h>
#include <stdint.h>

#define NH   8
#define DIM  512
#define NP   1024
#define MNP  4096
#define BS   4
#define TOPK 32
#define DH   64

typedef unsigned short u16;
typedef __attribute__((ext_vector_type(8))) short bf16x8;
typedef __attribute__((ext_vector_type(4))) float f32x4;

__device__ __forceinline__ u16 f2bf(float f) {
    union { float f; unsigned u; } x; x.f = f;
    unsigned r = x.u + 0x7FFFu + ((x.u >> 16) & 1u);   // RNE
    return (u16)(r >> 16);
}
__device__ __forceinline__ float bf2f(u16 h) {
    union { unsigned u; float f; } x; x.u = ((unsigned)h) << 16;
    return x.f;
}
__device__ __forceinline__ unsigned pk2(float a, float b) {
    return (unsigned)f2bf(a) | ((unsigned)f2bf(b) << 16);
}

// async 16B global -> LDS (global_load_lds_dwordx4), wave-uniform base + lane*16
__device__ __forceinline__ void async16(const void* g, void* l) {
    __builtin_amdgcn_global_load_lds(
        (const __attribute__((address_space(1))) unsigned int*)g,
        (__attribute__((address_space(3))) unsigned int*)l, 16, 0, 0);
}

// ---------------- fp32 -> bf16, one pass, 8 elems/thread, 16B stores
// (was 4 elems + 8B stores at 4.0 TB/s; all segment boundaries are mult-of-8)
__global__ void cvt_all(const float* __restrict__ W1, const float* __restrict__ W2,
                        const float* __restrict__ W3, const float* __restrict__ q,
                        const float* __restrict__ k,  const float* __restrict__ v,
                        u16* __restrict__ wall, u16* __restrict__ act) {
    const size_t i = ((size_t)blockIdx.x * 256 + threadIdx.x) * 8;
    const float* s; u16* d;
    if (i < 786432) {
        d = wall + i;
        s = (i < 262144) ? W1 + i : (i < 524288) ? W2 + (i - 262144) : W3 + (i - 524288);
    } else {
        size_t j = i - 786432;
        d = act + j;
        s = (j < 2097152) ? q + j : (j < 10485760) ? k + (j - 2097152) : v + (j - 10485760);
    }
    float4 v0 = *(const float4*)s;
    float4 v1 = *(const float4*)(s + 4);
    uint4 o = { pk2(v0.x, v0.y), pk2(v0.z, v0.w), pk2(v1.x, v1.y), pk2(v1.z, v1.w) };
    *(uint4*)d = o;
}

// ---------------- projection GEMM (r8 structure, unchanged — confirmed at the
// ~6.5 TB/s staging-supply ceiling): BM=256 BN=128 BK=32, 512 thr, 8 waves,
// triple-buffered counted vmcnt, pair-packed XOR-swizzled LDS.
__global__ __launch_bounds__(512, 4)
void proj_gemm(const u16* __restrict__ act, const u16* __restrict__ wall,
               const float* __restrict__ b1, const float* __restrict__ b2,
               const float* __restrict__ b3, u16* __restrict__ outall) {
    __shared__ u16 As[3][128 * 64];    // 256 rows pair-packed -> 128 phys x 64
    __shared__ u16 Bs[3][64 * 64];     // 128 rows pair-packed ->  64 phys x 64

    const int bid = blockIdx.x;        // 0..575
    const int x = bid / 144;
    const int t = bid % 144;
    int z, y;
    if (t < 16)      { z = 0; y = t; }           // q: M=4096  (16 tiles)
    else if (t < 80) { z = 1; y = t - 16; }      // k: M=16384 (64 tiles)
    else             { z = 2; y = t - 80; }      // v: M=16384 (64 tiles)

    const size_t aoff = (z == 0) ? 0u : (z == 1) ? 2097152u : 10485760u;
    const u16* A = act + aoff;
    const u16* W = wall + (size_t)z * 262144;
    const float* bias = (z == 0) ? b1 : (z == 1) ? b2 : b3;
    u16* C = outall + aoff;

    const int tid  = threadIdx.x;      // 0..511
    const int bm   = y * 256;
    const int bn   = x * 128;
    const int wave = tid >> 6;
    const int lane = tid & 63;
    const int wm   = (wave & 3) * 64;  // 4 m-waves
    const int wn   = (wave >> 2) * 64; // 2 n-waves
    const int l16  = lane & 15;
    const int quad = lane >> 4;

    const int pA   = tid >> 3;                 // 0..63
    const int q3   = tid & 7;
    const int posA = q3 ^ (pA & 7);
    const int hA   = posA >> 2;
    const int gA   = posA & 3;
    const int rA   = 2 * pA + hA;              // 0..127 (+128 for 2nd A chunk)
    const u16* Asrc = A + (size_t)(bm + rA) * 512 + gA * 8;
    const u16* Bsrc = W + (size_t)(bn + rA) * 512 + gA * 8;   // B rows 0..127

    f32x4 acc[4][4] = {};

    #define STAGE(buf, k0)                                                     \
        async16(Asrc + (k0),               &As[buf][tid * 8]);                 \
        async16(Asrc + 128 * 512 + (k0),   &As[buf][tid * 8 + 4096]);          \
        async16(Bsrc + (k0),               &Bs[buf][tid * 8]);

    STAGE(0, 0);
    STAGE(1, 32);

#pragma unroll
    for (int kt = 0; kt < 16; kt++) {
        const int cur = kt % 3;
        if (kt < 14) {
            STAGE((kt + 2) % 3, (kt + 2) * 32);  // prefetch tile kt+2
            asm volatile("s_waitcnt vmcnt(6)" ::: "memory");
        } else if (kt == 14) {
            asm volatile("s_waitcnt vmcnt(3)" ::: "memory");
        } else {
            asm volatile("s_waitcnt vmcnt(0)" ::: "memory");
        }
        __builtin_amdgcn_s_barrier();        // all waves: tile kt resident
        {
            bf16x8 af[4], bfr[4];
#pragma unroll
            for (int i = 0; i < 4; i++) {
                int ra = wm + i * 16 + l16;          // 0..255
                af[i] = *(const bf16x8*)(&As[cur][(ra >> 1) * 64 +
                          (((((ra & 1) << 2) | quad) ^ ((ra >> 1) & 7)) << 3)]);
            }
#pragma unroll
            for (int j = 0; j < 4; j++) {
                int rb = wn + j * 16 + l16;          // 0..127
                bfr[j] = *(const bf16x8*)(&Bs[cur][(rb >> 1) * 64 +
                          (((((rb & 1) << 2) | quad) ^ ((rb >> 1) & 7)) << 3)]);
            }
#pragma unroll
            for (int i = 0; i < 4; i++)
#pragma unroll
                for (int j = 0; j < 4; j++)
                    acc[i][j] = __builtin_amdgcn_mfma_f32_16x16x32_bf16(
                        af[i], bfr[j], acc[i][j], 0, 0, 0);
        }
        __builtin_amdgcn_s_barrier();
    }
    #undef STAGE

    // C/D layout: col=lane&15, row=quad*4+reg
#pragma unroll
    for (int i = 0; i < 4; i++) {
        int row = bm + wm + i * 16 + quad * 4;
#pragma unroll
        for (int j = 0; j < 4; j++) {
            int col = bn + wn + j * 16 + l16;
            float bv = bias[col];
#pragma unroll
            for (int r = 0; r < 4; r++)
                C[(size_t)(row + r) * 512 + col] = f2bf(acc[i][j][r] + bv);
        }
    }
}

// ---------------- top-k gather attention, head-split: one WAVE per
// (pair, head-half).  8192 waves = 32/CU (100% occupancy, was 16/CU) to hide
// the random-gather latency (K/V rows live in L3, miss L2).  Output elems
// [hw*256, hw*256+256) need exactly heads hw*4..hw*4+3 — the ones this wave
// scores — so waves stay fully independent (wave-private LDS, no barriers).
__global__ __launch_bounds__(256, 8)
void attn_kernel(const u16* __restrict__ Qh, const u16* __restrict__ Kh,
                 const u16* __restrict__ Vh, const int* __restrict__ rns,
                 float* __restrict__ out) {
    __shared__ float sq[4][512];        // q row fp32, wave-private
    __shared__ float swt[4][32 * 5];    // weights [slot][head-in-half], pad 5
    __shared__ int   srw[4][TOPK];      // gathered row offsets

    const int wv   = threadIdx.x >> 6;
    const int lane = threadIdx.x & 63;
    const int gw   = blockIdx.x * 4 + wv;   // 0..8191
    const int pair = gw >> 1;               // (n,b) id 0..4095
    const int hw   = gw & 1;                // head half 0..1
    const int n = pair >> 2;
    const int b = pair & 3;
    const int s   = lane >> 1;   // slot
    const int sub = lane & 1;    // dim half (32-dim)

    int myidx = rns[(b * NP + n) * TOPK + s];
    int myrow = (myidx * BS + b) * DIM;
    if (sub == 0) srw[wv][s] = myrow;

    // dedupe: dup iff an earlier slot has the same index (matches ref set-mask)
    bool dup = false;
#pragma unroll
    for (int j = 0; j < TOPK; j++) {
        int other = __shfl(myidx, j * 2, 64);
        dup = dup || ((j < s) && (other == myidx));
    }

    // q row -> LDS fp32 (16B bf16 load per lane)
    {
        const u16* qrow = Qh + (size_t)pair * DIM;
        uint4 qv = *(const uint4*)(qrow + lane * 8);
        float4 f0 = { bf2f((u16)qv.x), bf2f((u16)(qv.x >> 16)),
                      bf2f((u16)qv.y), bf2f((u16)(qv.y >> 16)) };
        float4 f1 = { bf2f((u16)qv.z), bf2f((u16)(qv.z >> 16)),
                      bf2f((u16)qv.w), bf2f((u16)(qv.w >> 16)) };
        *(float4*)(&sq[wv][lane * 8])     = f0;
        *(float4*)(&sq[wv][lane * 8 + 4]) = f1;
    }
    __builtin_amdgcn_wave_barrier();   // wave-private LDS: scheduling pin only

    // scores for this wave's 4 heads: lane = (slot, 32-dim half)
    const float* qw = sq[wv];
    float sc[4];
#pragma unroll
    for (int j = 0; j < 4; j++) {
        const int h = hw * 4 + j;
        const u16* kp = Kh + myrow + h * DH + sub * 32;
        const float* qp = qw + h * DH + sub * 32;
        float acc = 0.f;
#pragma unroll
        for (int d = 0; d < 32; d += 8) {
            uint4 kv = *(const uint4*)(kp + d);
            acc += qp[d + 0] * bf2f((u16)kv.x) + qp[d + 1] * bf2f((u16)(kv.x >> 16))
                 + qp[d + 2] * bf2f((u16)kv.y) + qp[d + 3] * bf2f((u16)(kv.y >> 16))
                 + qp[d + 4] * bf2f((u16)kv.z) + qp[d + 5] * bf2f((u16)(kv.z >> 16))
                 + qp[d + 6] * bf2f((u16)kv.w) + qp[d + 7] * bf2f((u16)(kv.w >> 16));
        }
        sc[j] = acc;
    }
#pragma unroll
    for (int j = 0; j < 4; j++) {
        sc[j] += __shfl_xor(sc[j], 1, 64);
        sc[j] = dup ? -1e30f : sc[j] * 0.125f;
    }
    // softmax over 32 slots via stride-{2..32} butterflies
    float w[4];
#pragma unroll
    for (int j = 0; j < 4; j++) {
        float m = sc[j];
        m = fmaxf(m, __shfl_xor(m, 2, 64));
        m = fmaxf(m, __shfl_xor(m, 4, 64));
        m = fmaxf(m, __shfl_xor(m, 8, 64));
        m = fmaxf(m, __shfl_xor(m, 16, 64));
        m = fmaxf(m, __shfl_xor(m, 32, 64));
        float e = __expf(sc[j] - m);
        float t = e;
        t += __shfl_xor(t, 2, 64);
        t += __shfl_xor(t, 4, 64);
        t += __shfl_xor(t, 8, 64);
        t += __shfl_xor(t, 16, 64);
        t += __shfl_xor(t, 32, 64);
        w[j] = e / t;
    }
    if (sub == 0) {
#pragma unroll
        for (int j = 0; j < 4; j++) swt[wv][s * 5 + j] = w[j];
    }
    __builtin_amdgcn_wave_barrier();

    // V phase: lane covers 4 output elems (8B V load) x 32 slots.
    // global head of elem block = hw*4 + (lane>>4) == this wave's head (lane>>4)
    const int hj = lane >> 4;
    const int e4 = hw * 256 + lane * 4;
    float a[4] = {0, 0, 0, 0};
#pragma unroll 8
    for (int si = 0; si < TOPK; si++) {
        int   row = srw[wv][si];              // broadcast read
        float wgt = swt[wv][si * 5 + hj];
        uint2 vv = *(const uint2*)(Vh + row + e4);
        a[0] += wgt * bf2f((u16)vv.x); a[1] += wgt * bf2f((u16)(vv.x >> 16));
        a[2] += wgt * bf2f((u16)vv.y); a[3] += wgt * bf2f((u16)(vv.y >> 16));
    }
    float4 o0 = {a[0], a[1], a[2], a[3]};
    *(float4*)(out + (size_t)pair * DIM + e4) = o0;
}

extern "C" void kernel_launch(void* const* d_in, const int* in_sizes, int n_in,
                              void* d_out, int out_size, void* d_ws, size_t ws_size,
                              hipStream_t stream) {
    const float* q  = (const float*)d_in[0];
    const float* k  = (const float*)d_in[1];
    const float* v  = (const float*)d_in[2];
    const int* rns  = (const int*)d_in[3];
    const float* W1 = (const float*)d_in[4];
    const float* b1 = (const float*)d_in[5];
    const float* W2 = (const float*)d_in[6];
    const float* b2 = (const float*)d_in[7];
    const float* W3 = (const float*)d_in[8];
    const float* b3 = (const float*)d_in[9];
    float* out = (float*)d_out;

    u16* ws   = (u16*)d_ws;
    u16* wall = ws;                        // 3 * 512*512 bf16 weights
    u16* act  = wall + 786432;             // q(2097152) | k(8388608) | v(8388608)
    u16* proj = act + 18874368;            // Qh | Kh | Vh, same offsets
    u16* Qh = proj;
    u16* Kh = proj + 2097152;
    u16* Vh = proj + 10485760;

    cvt_all<<<9600, 256, 0, stream>>>(W1, W2, W3, q, k, v, wall, act);
    proj_gemm<<<576, 512, 0, stream>>>(act, wall, b1, b2, b3, proj);
    attn_kernel<<<NP * BS / 2, 256, 0, stream>>>(Qh, Kh, Vh, rns, out);
}